// Round 1
// baseline (170.729 us; speedup 1.0000x reference)
//
#include <hip/hip_runtime.h>

// Problem constants (StochPool: B=64, N_PER=1024, D=256, K=64, DEG=16)
#define NN 65536           // total nodes
#define DD 256             // feature dim
#define KK 64              // pools per graph
#define NPG 1024           // nodes per graph

// d_out layout (flat float32, outputs concatenated in return order)
#define OUT_OFF   0          // (4096, 256)
#define ADJ_OFF   1048576    // (64, 64, 64)
#define LINK_OFF  1310720    // scalar
#define ENT_OFF   1310721    // scalar
#define BATCH_OFF 1310722    // (4096,) as float
#define BPTR_OFF  1314818    // (65,) as float

// ws layout (bytes)
#define WS_ASSIGN 0          // int32 x 65536
#define WS_S1     262144     // float x 65536
#define WS_C      524288     // float x 4096   (StS diagonal accum)
#define WS_SQA    540672     // float x 64
#define WS_CROSS  540928     // float x 64
#define WS_ENT    541184     // float x 1

// ---------------------------------------------------------------------------
// Kernel 1: logits GEMM + argmax/softmax stats per node.
// 256 blocks x 256 threads; each block owns 256 consecutive nodes.
// Thread t: kq = t&7 -> k in [kq*8, kq*8+8); ng = t>>3 -> nodes ng + 32*i.
// LDS: full W [256][64] (64KB) + x chunk [256 nodes][68 pad] (68KB, reused for z).
// ---------------------------------------------------------------------------
__global__ __launch_bounds__(256, 1) void pool_assign_kernel(
    const float* __restrict__ x, const float* __restrict__ Wm,
    const float* __restrict__ bvec, const float* __restrict__ gum,
    int* __restrict__ assign, float* __restrict__ s1g,
    float* __restrict__ c_acc, float* __restrict__ ent_acc)
{
  __shared__ float lds_w[256 * 64];
  __shared__ float lds_x[256 * 68];   // x chunk, later reused as z[node][68]
  __shared__ float esum[4];
  const int t   = threadIdx.x;
  const int kq  = t & 7;
  const int ng  = t >> 3;
  const int nb0 = blockIdx.x << 8;

  // stage full W, coalesced (16 float4 per thread)
  #pragma unroll
  for (int i = 0; i < 16; ++i) {
    int off = i * 1024 + t * 4;
    *(float4*)(&lds_w[off]) = *(const float4*)(Wm + off);
  }
  float bk[8];
  #pragma unroll
  for (int j = 0; j < 8; ++j) bk[j] = bvec[kq * 8 + j];

  float acc[8][8];
  #pragma unroll
  for (int i = 0; i < 8; ++i)
    #pragma unroll
    for (int j = 0; j < 8; ++j) acc[i][j] = 0.f;

  for (int ch = 0; ch < 4; ++ch) {
    const int d0 = ch << 6;
    // stage x[nb0 + 0..255][d0 .. d0+63] -> lds_x[node][0..63] (stride 68)
    #pragma unroll
    for (int it = 0; it < 16; ++it) {
      int r  = it * 16 + (t >> 4);
      int fi = (t & 15) << 2;
      *(float4*)(&lds_x[r * 68 + fi]) =
          *(const float4*)(x + (size_t)(nb0 + r) * DD + d0 + fi);
    }
    __syncthreads();
    #pragma unroll
    for (int d4 = 0; d4 < 16; ++d4) {
      float4 xv[8];
      #pragma unroll
      for (int i = 0; i < 8; ++i)
        xv[i] = *(const float4*)(&lds_x[(ng + 32 * i) * 68 + (d4 << 2)]);
      float4 wa[4], wb[4];
      #pragma unroll
      for (int m = 0; m < 4; ++m) {
        const float* wr = &lds_w[(d0 + (d4 << 2) + m) * 64 + kq * 8];
        wa[m] = *(const float4*)wr;
        wb[m] = *(const float4*)(wr + 4);
      }
      #pragma unroll
      for (int i = 0; i < 8; ++i) {
        const float* xp = (const float*)&xv[i];
        #pragma unroll
        for (int m = 0; m < 4; ++m) {
          float xs = xp[m];
          acc[i][0] = fmaf(xs, wa[m].x, acc[i][0]);
          acc[i][1] = fmaf(xs, wa[m].y, acc[i][1]);
          acc[i][2] = fmaf(xs, wa[m].z, acc[i][2]);
          acc[i][3] = fmaf(xs, wa[m].w, acc[i][3]);
          acc[i][4] = fmaf(xs, wb[m].x, acc[i][4]);
          acc[i][5] = fmaf(xs, wb[m].y, acc[i][5]);
          acc[i][6] = fmaf(xs, wb[m].z, acc[i][6]);
          acc[i][7] = fmaf(xs, wb[m].w, acc[i][7]);
        }
      }
    }
    __syncthreads();
  }

  // z = acc + b + gumbel -> lds_x (reused, stride 68)
  #pragma unroll
  for (int i = 0; i < 8; ++i) {
    int nl = ng + 32 * i;
    const float* gp = gum + (size_t)(nb0 + nl) * KK + kq * 8;
    float4 g0 = *(const float4*)gp;
    float4 g1 = *(const float4*)(gp + 4);
    float4 z0, z1;
    z0.x = acc[i][0] + bk[0] + g0.x;
    z0.y = acc[i][1] + bk[1] + g0.y;
    z0.z = acc[i][2] + bk[2] + g0.z;
    z0.w = acc[i][3] + bk[3] + g0.w;
    z1.x = acc[i][4] + bk[4] + g1.x;
    z1.y = acc[i][5] + bk[5] + g1.y;
    z1.z = acc[i][6] + bk[6] + g1.z;
    z1.w = acc[i][7] + bk[7] + g1.w;
    *(float4*)(&lds_x[nl * 68 + kq * 8])     = z0;
    *(float4*)(&lds_x[nl * 68 + kq * 8 + 4]) = z1;
  }
  __syncthreads();

  // phase 2: one node per thread — argmax, softmax max-prob, entropy
  {
    const int node = t;
    float z[64];
    #pragma unroll
    for (int q = 0; q < 16; ++q)
      *(float4*)(&z[q * 4]) = *(const float4*)(&lds_x[node * 68 + q * 4]);
    float zmax = z[0]; int amax = 0;
    #pragma unroll
    for (int k = 1; k < 64; ++k)
      if (z[k] > zmax) { zmax = z[k]; amax = k; }   // strict > keeps first max
    float sum = 0.f;
    #pragma unroll
    for (int k = 0; k < 64; ++k) sum += expf(z[k] - zmax);
    float p  = 1.0f / sum;                 // = softmax value at argmax
    float s1 = (1.0f - p) + p;             // straight-through value (≈1)
    float ent = -s1 * logf(s1 + 1e-15f);   // non-argmax terms are exactly 0
    size_t n_g = (size_t)nb0 + node;
    int g = (int)(n_g >> 10);
    assign[n_g] = amax;
    s1g[n_g]    = s1;
    atomicAdd(&c_acc[g * 64 + amax], s1 * s1);

    float e = ent;
    #pragma unroll
    for (int off = 32; off; off >>= 1) e += __shfl_down(e, off, 64);
    if ((t & 63) == 0) esum[t >> 6] = e;
    __syncthreads();
    if (t == 0) atomicAdd(ent_acc, esum[0] + esum[1] + esum[2] + esum[3]);
  }
}

// ---------------------------------------------------------------------------
// Kernel 2: pooled features out[g*K + k][d] = sum_{assign=k} s1 * x[n][d].
// 512 blocks (8 chunks of 128 nodes per graph) x 256 threads (one d each).
// LDS accumulator [64][256] then atomic-add into global out.
// ---------------------------------------------------------------------------
__global__ __launch_bounds__(256, 2) void feat_pool_kernel(
    const float* __restrict__ x, const int* __restrict__ assign,
    const float* __restrict__ s1, float* __restrict__ out)
{
  __shared__ float facc[64 * 256];
  const int t = threadIdx.x;
  #pragma unroll
  for (int i = 0; i < 64; ++i) facc[i * 256 + t] = 0.f;
  __syncthreads();
  const int blk = blockIdx.x;
  const int g   = blk >> 3;
  const int nb0 = blk << 7;   // 128 nodes per block
  #pragma unroll 4
  for (int nl = 0; nl < 128; ++nl) {
    int n   = nb0 + nl;
    int a   = assign[n];
    float w = s1[n];
    float xv = x[(size_t)n * DD + t];
    facc[a * 256 + t] += w * xv;
  }
  __syncthreads();
  float* og = out + (size_t)g * KK * DD;
  #pragma unroll
  for (int r = 0; r < 64; ++r)
    atomicAdd(&og[r * 256 + t], facc[r * 256 + t]);
}

// ---------------------------------------------------------------------------
// Kernel 3: edges -> out_adj scatter + per-graph sum(w^2) and cross terms.
// 1024 blocks x 256 threads x 4 edges; each block within one graph.
// ---------------------------------------------------------------------------
__global__ __launch_bounds__(256) void edge_kernel(
    const int* __restrict__ src, const int* __restrict__ dst,
    const float* __restrict__ ew, const int* __restrict__ assign,
    const float* __restrict__ s1, float* __restrict__ out_adj,
    float* __restrict__ sqA, float* __restrict__ crossA)
{
  const int t = threadIdx.x;
  const int blk = blockIdx.x;
  const int g = blk >> 4;               // 16 blocks per graph (16384 edges)
  float* adjg = out_adj + (size_t)g * 4096;
  float sq = 0.f, cr = 0.f;
  #pragma unroll
  for (int i = 0; i < 4; ++i) {
    int e = blk * 1024 + i * 256 + t;
    int u = src[e], v = dst[e];
    float w = ew[e];
    int au = assign[u], av = assign[v];
    float contrib = w * s1[u] * s1[v];
    atomicAdd(&adjg[au * 64 + av], contrib);
    sq += w * w;
    if (au == av) cr += contrib;
  }
  #pragma unroll
  for (int off = 32; off; off >>= 1) {
    sq += __shfl_down(sq, off, 64);
    cr += __shfl_down(cr, off, 64);
  }
  if ((t & 63) == 0) {
    atomicAdd(&sqA[g], sq);
    atomicAdd(&crossA[g], cr);
  }
}

// ---------------------------------------------------------------------------
// Kernel 4: link/entropy scalars + batch / batch_ptr tails.
// ---------------------------------------------------------------------------
__global__ __launch_bounds__(256) void finalize_kernel(
    const float* __restrict__ c, const float* __restrict__ sqA,
    const float* __restrict__ crossA, const float* __restrict__ ent_acc,
    float* __restrict__ out)
{
  const int t = threadIdx.x;
  float link = 0.f;
  if (t < 64) {
    const float* cg = c + t * 64;
    float ssq = 0.f;
    #pragma unroll
    for (int k = 0; k < 64; ++k) ssq += cg[k] * cg[k];
    float val = sqA[t] - 2.0f * crossA[t] + ssq;
    link = sqrtf(fmaxf(val, 0.f)) / 16384.0f;   // e_per = 16384
  }
  #pragma unroll
  for (int off = 32; off; off >>= 1) link += __shfl_down(link, off, 64);
  if (t == 0) {
    out[LINK_OFF] = link / 64.0f;
    out[ENT_OFF]  = ent_acc[0] / (float)NN;
  }
  for (int r = t; r < 4096; r += 256) out[BATCH_OFF + r] = (float)(r >> 6);
  for (int i = t; i < 65; i += 256)   out[BPTR_OFF + i]  = (float)(i << 6);
}

extern "C" void kernel_launch(void* const* d_in, const int* in_sizes, int n_in,
                              void* d_out, int out_size, void* d_ws, size_t ws_size,
                              hipStream_t stream) {
  const float* x    = (const float*)d_in[0];
  const float* ew   = (const float*)d_in[1];
  const float* Wm   = (const float*)d_in[2];
  const float* bvec = (const float*)d_in[3];
  const float* gum  = (const float*)d_in[4];
  const int*   eidx = (const int*)d_in[5];
  float* out = (float*)d_out;
  char*  ws  = (char*)d_ws;

  int*   assign = (int*)(ws + WS_ASSIGN);
  float* s1     = (float*)(ws + WS_S1);
  float* c      = (float*)(ws + WS_C);
  float* sqA    = (float*)(ws + WS_SQA);
  float* crossA = (float*)(ws + WS_CROSS);
  float* entacc = (float*)(ws + WS_ENT);

  const int E = in_sizes[1];   // 1048576

  // zero accumulation targets (re-done every replay; harness never re-poisons)
  hipMemsetAsync(d_out, 0, (size_t)(ADJ_OFF + 64 * 64 * 64) * 4, stream);
  hipMemsetAsync(ws + WS_C, 0, (WS_ENT + 4) - WS_C, stream);

  pool_assign_kernel<<<256, 256, 0, stream>>>(x, Wm, bvec, gum, assign, s1, c, entacc);
  feat_pool_kernel<<<512, 256, 0, stream>>>(x, assign, s1, out + OUT_OFF);
  edge_kernel<<<E / 1024, 256, 0, stream>>>(eidx, eidx + E, ew, assign, s1,
                                            out + ADJ_OFF, sqA, crossA);
  finalize_kernel<<<1, 256, 0, stream>>>(c, sqA, crossA, entacc, out);
}

// Round 2
// 160.725 us; speedup vs baseline: 1.0622x; 1.0622x over previous
//
#include <hip/hip_runtime.h>

// Problem constants (StochPool: B=64, N_PER=1024, D=256, K=64, DEG=16)
#define NN 65536           // total nodes
#define DD 256             // feature dim
#define KK 64              // pools per graph
#define NPG 1024           // nodes per graph

// d_out layout (flat float32, outputs concatenated in return order)
#define OUT_OFF   0          // (4096, 256)
#define ADJ_OFF   1048576    // (64, 64, 64)
#define LINK_OFF  1310720    // scalar
#define ENT_OFF   1310721    // scalar
#define BATCH_OFF 1310722    // (4096,) as float
#define BPTR_OFF  1314818    // (65,) as float

// ws layout (bytes)
#define WS_ASSIGN 0          // int32 x 65536
#define WS_S1     262144     // float x 65536
#define WS_C      524288     // float x 4096   (StS diagonal accum)
#define WS_SQA    540672     // float x 64
#define WS_CROSS  540928     // float x 64
#define WS_ENT    541184     // float x 1

// ---------------------------------------------------------------------------
// Kernel 1: logits GEMM + argmax/softmax stats per node.
// 512 blocks x 256 threads; each block owns 128 consecutive nodes.
// Thread t: kq = t&7 -> k in [kq*8, kq*8+8); ng = t>>3 -> nodes ng + 32*i (i<4).
// LDS: W d-slice [64][64] (16KB, restaged per chunk) + x chunk [128][68] (34KB,
// reused for z). ~50KB total -> 3 blocks/CU (vs 1 before).
// ---------------------------------------------------------------------------
__global__ __launch_bounds__(256, 3) void pool_assign_kernel(
    const float* __restrict__ x, const float* __restrict__ Wm,
    const float* __restrict__ bvec, const float* __restrict__ gum,
    int* __restrict__ assign, float* __restrict__ s1g,
    float* __restrict__ c_acc, float* __restrict__ ent_acc)
{
  __shared__ float lds_w[64 * 64];    // W slice: [d within chunk][k]
  __shared__ float lds_x[128 * 68];   // x chunk, later reused as z[node][68]
  __shared__ float esum[4];
  const int t   = threadIdx.x;
  const int kq  = t & 7;
  const int ng  = t >> 3;
  const int nb0 = blockIdx.x << 7;    // 128 nodes per block

  float bk[8];
  #pragma unroll
  for (int j = 0; j < 8; ++j) bk[j] = bvec[kq * 8 + j];

  float acc[4][8];
  #pragma unroll
  for (int i = 0; i < 4; ++i)
    #pragma unroll
    for (int j = 0; j < 8; ++j) acc[i][j] = 0.f;

  for (int ch = 0; ch < 4; ++ch) {
    const int d0 = ch << 6;
    // stage W rows d0..d0+63 (4096 contiguous floats starting at d0*64)
    #pragma unroll
    for (int i = 0; i < 4; ++i) {
      int off = i * 1024 + t * 4;
      *(float4*)(&lds_w[off]) = *(const float4*)(Wm + d0 * 64 + off);
    }
    // stage x[nb0 + 0..127][d0 .. d0+63] -> lds_x[node][0..63] (stride 68)
    #pragma unroll
    for (int it = 0; it < 8; ++it) {
      int r  = it * 16 + (t >> 4);
      int fi = (t & 15) << 2;
      *(float4*)(&lds_x[r * 68 + fi]) =
          *(const float4*)(x + (size_t)(nb0 + r) * DD + d0 + fi);
    }
    __syncthreads();
    #pragma unroll
    for (int d4 = 0; d4 < 16; ++d4) {
      float4 xv[4];
      #pragma unroll
      for (int i = 0; i < 4; ++i)
        xv[i] = *(const float4*)(&lds_x[(ng + 32 * i) * 68 + (d4 << 2)]);
      float4 wa[4], wb[4];
      #pragma unroll
      for (int m = 0; m < 4; ++m) {
        const float* wr = &lds_w[((d4 << 2) + m) * 64 + kq * 8];
        wa[m] = *(const float4*)wr;
        wb[m] = *(const float4*)(wr + 4);
      }
      #pragma unroll
      for (int i = 0; i < 4; ++i) {
        const float* xp = (const float*)&xv[i];
        #pragma unroll
        for (int m = 0; m < 4; ++m) {
          float xs = xp[m];
          acc[i][0] = fmaf(xs, wa[m].x, acc[i][0]);
          acc[i][1] = fmaf(xs, wa[m].y, acc[i][1]);
          acc[i][2] = fmaf(xs, wa[m].z, acc[i][2]);
          acc[i][3] = fmaf(xs, wa[m].w, acc[i][3]);
          acc[i][4] = fmaf(xs, wb[m].x, acc[i][4]);
          acc[i][5] = fmaf(xs, wb[m].y, acc[i][5]);
          acc[i][6] = fmaf(xs, wb[m].z, acc[i][6]);
          acc[i][7] = fmaf(xs, wb[m].w, acc[i][7]);
        }
      }
    }
    __syncthreads();
  }

  // z = acc + b + gumbel -> lds_x (reused, stride 68)
  #pragma unroll
  for (int i = 0; i < 4; ++i) {
    int nl = ng + 32 * i;
    const float* gp = gum + (size_t)(nb0 + nl) * KK + kq * 8;
    float4 g0 = *(const float4*)gp;
    float4 g1 = *(const float4*)(gp + 4);
    float4 z0, z1;
    z0.x = acc[i][0] + bk[0] + g0.x;
    z0.y = acc[i][1] + bk[1] + g0.y;
    z0.z = acc[i][2] + bk[2] + g0.z;
    z0.w = acc[i][3] + bk[3] + g0.w;
    z1.x = acc[i][4] + bk[4] + g1.x;
    z1.y = acc[i][5] + bk[5] + g1.y;
    z1.z = acc[i][6] + bk[6] + g1.z;
    z1.w = acc[i][7] + bk[7] + g1.w;
    *(float4*)(&lds_x[nl * 68 + kq * 8])     = z0;
    *(float4*)(&lds_x[nl * 68 + kq * 8 + 4]) = z1;
  }
  __syncthreads();

  // phase 2: one node per thread (first 128 threads) — argmax, softmax, entropy
  float ent = 0.f;
  if (t < 128) {
    const int node = t;
    float z[64];
    #pragma unroll
    for (int q = 0; q < 16; ++q)
      *(float4*)(&z[q * 4]) = *(const float4*)(&lds_x[node * 68 + q * 4]);
    float zmax = z[0]; int amax = 0;
    #pragma unroll
    for (int k = 1; k < 64; ++k)
      if (z[k] > zmax) { zmax = z[k]; amax = k; }   // strict > keeps first max
    float sum = 0.f;
    #pragma unroll
    for (int k = 0; k < 64; ++k) sum += expf(z[k] - zmax);
    float p  = 1.0f / sum;                 // = softmax value at argmax
    float s1 = (1.0f - p) + p;             // straight-through value (≈1)
    ent = -s1 * logf(s1 + 1e-15f);         // non-argmax terms are exactly 0
    size_t n_g = (size_t)nb0 + node;
    int g = (int)(n_g >> 10);
    assign[n_g] = amax;
    s1g[n_g]    = s1;
    atomicAdd(&c_acc[g * 64 + amax], s1 * s1);
  }
  #pragma unroll
  for (int off = 32; off; off >>= 1) ent += __shfl_down(ent, off, 64);
  if ((t & 63) == 0) esum[t >> 6] = ent;
  __syncthreads();
  if (t == 0) atomicAdd(ent_acc, esum[0] + esum[1] + esum[2] + esum[3]);
}

// ---------------------------------------------------------------------------
// Kernel 2: pooled features out[g*K + k][d] = sum_{assign=k} s1 * x[n][d].
// 256 blocks = (graph g, 64-dim slice ds) x 256 threads.
// Thread t: node-lane nl = t>>6 (wave id), dim d = t&63.
// 4 private LDS copies (one per wave) -> zero atomics, zero bank conflicts
// (whole wave shares one node -> one cluster -> 64 consecutive dims).
// Plain-store writeout (block exclusively owns its (g, dslice)).
// ---------------------------------------------------------------------------
__global__ __launch_bounds__(256, 2) void feat_pool_kernel(
    const float* __restrict__ x, const int* __restrict__ assign,
    const float* __restrict__ s1, float* __restrict__ out)
{
  __shared__ float facc[4 * 64 * 64];   // [copy nl][cluster][dim] 64 KB
  const int t  = threadIdx.x;
  const int g  = blockIdx.x >> 2;
  const int ds = blockIdx.x & 3;
  const int nl = t >> 6;
  const int d  = t & 63;
  #pragma unroll
  for (int i = 0; i < 64; ++i) facc[i * 256 + t] = 0.f;
  __syncthreads();
  const int n0 = g << 10;
  for (int it = 0; it < 256; ++it) {
    int n   = n0 + it * 4 + nl;
    int a   = assign[n];
    float w = s1[n];
    float xv = x[(size_t)n * DD + ds * 64 + d];
    atomicAdd(&facc[nl * 4096 + a * 64 + d], w * xv);   // ds_add_f32, wave-private copy
  }
  __syncthreads();
  float* og = out + ((size_t)g * KK) * DD + ds * 64;
  #pragma unroll
  for (int r = 0; r < 16; ++r) {
    int k = r * 4 + nl;
    int cell = k * 64 + d;
    float s = facc[cell] + facc[4096 + cell] + facc[8192 + cell] + facc[12288 + cell];
    og[(size_t)k * DD + d] = s;
  }
}

// ---------------------------------------------------------------------------
// Kernel 3: edges -> out_adj via per-graph LDS accumulation. One block per
// graph (1024 threads x 16 edges). Plain-store writeout, no global atomics.
// ---------------------------------------------------------------------------
__global__ __launch_bounds__(1024, 4) void edge_kernel(
    const int* __restrict__ src, const int* __restrict__ dst,
    const float* __restrict__ ew, const int* __restrict__ assign,
    const float* __restrict__ s1, float* __restrict__ out_adj,
    float* __restrict__ sqA, float* __restrict__ crossA)
{
  __shared__ float adj[4096];           // 64x64 pooled adjacency
  __shared__ float redsq[16], redcr[16];
  const int t = threadIdx.x;
  const int g = blockIdx.x;
  #pragma unroll
  for (int i = 0; i < 4; ++i) adj[i * 1024 + t] = 0.f;
  __syncthreads();
  const int e0 = g << 14;               // 16384 edges per graph
  float sq = 0.f, cr = 0.f;
  #pragma unroll 4
  for (int i = 0; i < 16; ++i) {
    int e = e0 + i * 1024 + t;
    int u = src[e], v = dst[e];
    float w = ew[e];
    int au = assign[u], av = assign[v];
    float contrib = w * s1[u] * s1[v];
    atomicAdd(&adj[au * 64 + av], contrib);   // ds_add_f32
    sq += w * w;
    if (au == av) cr += contrib;
  }
  #pragma unroll
  for (int off = 32; off; off >>= 1) {
    sq += __shfl_down(sq, off, 64);
    cr += __shfl_down(cr, off, 64);
  }
  if ((t & 63) == 0) { redsq[t >> 6] = sq; redcr[t >> 6] = cr; }
  __syncthreads();
  float* adjg = out_adj + (size_t)g * 4096;
  #pragma unroll
  for (int i = 0; i < 4; ++i) adjg[i * 1024 + t] = adj[i * 1024 + t];
  if (t == 0) {
    float a = 0.f, b2 = 0.f;
    #pragma unroll
    for (int i = 0; i < 16; ++i) { a += redsq[i]; b2 += redcr[i]; }
    sqA[g] = a;
    crossA[g] = b2;
  }
}

// ---------------------------------------------------------------------------
// Kernel 4: link/entropy scalars + batch / batch_ptr tails.
// ---------------------------------------------------------------------------
__global__ __launch_bounds__(256) void finalize_kernel(
    const float* __restrict__ c, const float* __restrict__ sqA,
    const float* __restrict__ crossA, const float* __restrict__ ent_acc,
    float* __restrict__ out)
{
  const int t = threadIdx.x;
  float link = 0.f;
  if (t < 64) {
    const float* cg = c + t * 64;
    float ssq = 0.f;
    #pragma unroll
    for (int k = 0; k < 64; ++k) ssq += cg[k] * cg[k];
    float val = sqA[t] - 2.0f * crossA[t] + ssq;
    link = sqrtf(fmaxf(val, 0.f)) / 16384.0f;   // e_per = 16384
  }
  #pragma unroll
  for (int off = 32; off; off >>= 1) link += __shfl_down(link, off, 64);
  if (t == 0) {
    out[LINK_OFF] = link / 64.0f;
    out[ENT_OFF]  = ent_acc[0] / (float)NN;
  }
  for (int r = t; r < 4096; r += 256) out[BATCH_OFF + r] = (float)(r >> 6);
  for (int i = t; i < 65; i += 256)   out[BPTR_OFF + i]  = (float)(i << 6);
}

extern "C" void kernel_launch(void* const* d_in, const int* in_sizes, int n_in,
                              void* d_out, int out_size, void* d_ws, size_t ws_size,
                              hipStream_t stream) {
  const float* x    = (const float*)d_in[0];
  const float* ew   = (const float*)d_in[1];
  const float* Wm   = (const float*)d_in[2];
  const float* bvec = (const float*)d_in[3];
  const float* gum  = (const float*)d_in[4];
  const int*   eidx = (const int*)d_in[5];
  float* out = (float*)d_out;
  char*  ws  = (char*)d_ws;

  int*   assign = (int*)(ws + WS_ASSIGN);
  float* s1     = (float*)(ws + WS_S1);
  float* c      = (float*)(ws + WS_C);
  float* sqA    = (float*)(ws + WS_SQA);
  float* crossA = (float*)(ws + WS_CROSS);
  float* entacc = (float*)(ws + WS_ENT);

  const int E = in_sizes[1];   // 1048576

  // zero only the atomic accumulators (c, sqA, crossA, ent) — everything in
  // d_out is now fully overwritten by plain stores.
  hipMemsetAsync(ws + WS_C, 0, (WS_ENT + 4) - WS_C, stream);

  pool_assign_kernel<<<512, 256, 0, stream>>>(x, Wm, bvec, gum, assign, s1, c, entacc);
  feat_pool_kernel<<<256, 256, 0, stream>>>(x, assign, s1, out + OUT_OFF);
  edge_kernel<<<64, 1024, 0, stream>>>(eidx, eidx + E, ew, assign, s1,
                                       out + ADJ_OFF, sqA, crossA);
  finalize_kernel<<<1, 256, 0, stream>>>(c, sqA, crossA, entacc, out);
}

// Round 3
// 104.482 us; speedup vs baseline: 1.6341x; 1.5383x over previous
//
#include <hip/hip_runtime.h>

// Problem constants (StochPool: B=64, N_PER=1024, D=256, K=64, DEG=16)
#define NN 65536           // total nodes
#define DD 256             // feature dim
#define KK 64              // pools per graph
#define NPG 1024           // nodes per graph

// d_out layout (flat float32, outputs concatenated in return order)
#define OUT_OFF   0          // (4096, 256)
#define ADJ_OFF   1048576    // (64, 64, 64)
#define LINK_OFF  1310720    // scalar
#define ENT_OFF   1310721    // scalar
#define BATCH_OFF 1310722    // (4096,) as float
#define BPTR_OFF  1314818    // (65,) as float

// ws layout (bytes)
#define WS_ASSIGN 0          // int32 x 65536
#define WS_S1     262144     // float x 65536
#define WS_C      524288     // float x 4096   (StS diagonal accum)
#define WS_SQA    540672     // float x 64
#define WS_CROSS  540928     // float x 64
#define WS_ENT    541184     // float x 1
#define WS_SORT   1048576    // int32 x 65536 (node ids sorted by cluster, per graph)
#define WS_GOFF   1310720    // int32 x 64*65 (per-graph bin offsets)

// ---------------------------------------------------------------------------
// Kernel 1: logits GEMM + argmax/softmax stats per node.
// 512 blocks x 256 threads; each block owns 128 consecutive nodes.
// LDS: W d-slice [64][64] (16KB, restaged per chunk) + x chunk [128][68] (34KB,
// reused for z). ~50KB total -> 3 blocks/CU.
// ---------------------------------------------------------------------------
__global__ __launch_bounds__(256, 3) void pool_assign_kernel(
    const float* __restrict__ x, const float* __restrict__ Wm,
    const float* __restrict__ bvec, const float* __restrict__ gum,
    int* __restrict__ assign, float* __restrict__ s1g,
    float* __restrict__ c_acc, float* __restrict__ ent_acc)
{
  __shared__ float lds_w[64 * 64];    // W slice: [d within chunk][k]
  __shared__ float lds_x[128 * 68];   // x chunk, later reused as z[node][68]
  __shared__ float esum[4];
  const int t   = threadIdx.x;
  const int kq  = t & 7;
  const int ng  = t >> 3;
  const int nb0 = blockIdx.x << 7;    // 128 nodes per block

  float bk[8];
  #pragma unroll
  for (int j = 0; j < 8; ++j) bk[j] = bvec[kq * 8 + j];

  float acc[4][8];
  #pragma unroll
  for (int i = 0; i < 4; ++i)
    #pragma unroll
    for (int j = 0; j < 8; ++j) acc[i][j] = 0.f;

  for (int ch = 0; ch < 4; ++ch) {
    const int d0 = ch << 6;
    #pragma unroll
    for (int i = 0; i < 4; ++i) {
      int off = i * 1024 + t * 4;
      *(float4*)(&lds_w[off]) = *(const float4*)(Wm + d0 * 64 + off);
    }
    #pragma unroll
    for (int it = 0; it < 8; ++it) {
      int r  = it * 16 + (t >> 4);
      int fi = (t & 15) << 2;
      *(float4*)(&lds_x[r * 68 + fi]) =
          *(const float4*)(x + (size_t)(nb0 + r) * DD + d0 + fi);
    }
    __syncthreads();
    #pragma unroll
    for (int d4 = 0; d4 < 16; ++d4) {
      float4 xv[4];
      #pragma unroll
      for (int i = 0; i < 4; ++i)
        xv[i] = *(const float4*)(&lds_x[(ng + 32 * i) * 68 + (d4 << 2)]);
      float4 wa[4], wb[4];
      #pragma unroll
      for (int m = 0; m < 4; ++m) {
        const float* wr = &lds_w[((d4 << 2) + m) * 64 + kq * 8];
        wa[m] = *(const float4*)wr;
        wb[m] = *(const float4*)(wr + 4);
      }
      #pragma unroll
      for (int i = 0; i < 4; ++i) {
        const float* xp = (const float*)&xv[i];
        #pragma unroll
        for (int m = 0; m < 4; ++m) {
          float xs = xp[m];
          acc[i][0] = fmaf(xs, wa[m].x, acc[i][0]);
          acc[i][1] = fmaf(xs, wa[m].y, acc[i][1]);
          acc[i][2] = fmaf(xs, wa[m].z, acc[i][2]);
          acc[i][3] = fmaf(xs, wa[m].w, acc[i][3]);
          acc[i][4] = fmaf(xs, wb[m].x, acc[i][4]);
          acc[i][5] = fmaf(xs, wb[m].y, acc[i][5]);
          acc[i][6] = fmaf(xs, wb[m].z, acc[i][6]);
          acc[i][7] = fmaf(xs, wb[m].w, acc[i][7]);
        }
      }
    }
    __syncthreads();
  }

  // z = acc + b + gumbel -> lds_x (reused, stride 68)
  #pragma unroll
  for (int i = 0; i < 4; ++i) {
    int nl = ng + 32 * i;
    const float* gp = gum + (size_t)(nb0 + nl) * KK + kq * 8;
    float4 g0 = *(const float4*)gp;
    float4 g1 = *(const float4*)(gp + 4);
    float4 z0, z1;
    z0.x = acc[i][0] + bk[0] + g0.x;
    z0.y = acc[i][1] + bk[1] + g0.y;
    z0.z = acc[i][2] + bk[2] + g0.z;
    z0.w = acc[i][3] + bk[3] + g0.w;
    z1.x = acc[i][4] + bk[4] + g1.x;
    z1.y = acc[i][5] + bk[5] + g1.y;
    z1.z = acc[i][6] + bk[6] + g1.z;
    z1.w = acc[i][7] + bk[7] + g1.w;
    *(float4*)(&lds_x[nl * 68 + kq * 8])     = z0;
    *(float4*)(&lds_x[nl * 68 + kq * 8 + 4]) = z1;
  }
  __syncthreads();

  // phase 2: one node per thread (first 128 threads) — argmax, softmax, entropy
  float ent = 0.f;
  if (t < 128) {
    const int node = t;
    float z[64];
    #pragma unroll
    for (int q = 0; q < 16; ++q)
      *(float4*)(&z[q * 4]) = *(const float4*)(&lds_x[node * 68 + q * 4]);
    float zmax = z[0]; int amax = 0;
    #pragma unroll
    for (int k = 1; k < 64; ++k)
      if (z[k] > zmax) { zmax = z[k]; amax = k; }   // strict > keeps first max
    float sum = 0.f;
    #pragma unroll
    for (int k = 0; k < 64; ++k) sum += expf(z[k] - zmax);
    float p  = 1.0f / sum;                 // = softmax value at argmax
    float s1 = (1.0f - p) + p;             // straight-through value (≈1)
    ent = -s1 * logf(s1 + 1e-15f);         // non-argmax terms are exactly 0
    size_t n_g = (size_t)nb0 + node;
    int g = (int)(n_g >> 10);
    assign[n_g] = amax;
    s1g[n_g]    = s1;
    atomicAdd(&c_acc[g * 64 + amax], s1 * s1);
  }
  #pragma unroll
  for (int off = 32; off; off >>= 1) ent += __shfl_down(ent, off, 64);
  if ((t & 63) == 0) esum[t >> 6] = ent;
  __syncthreads();
  if (t == 0) atomicAdd(ent_acc, esum[0] + esum[1] + esum[2] + esum[3]);
}

// ---------------------------------------------------------------------------
// Kernel 2a: per-graph counting sort of nodes by cluster.
// 64 blocks (one per graph) x 256 threads x 4 nodes.
// ---------------------------------------------------------------------------
__global__ __launch_bounds__(256) void sort_kernel(
    const int* __restrict__ assign, int* __restrict__ sorted,
    int* __restrict__ goff)
{
  __shared__ int hist[64];
  __shared__ int offs[65];
  __shared__ int cursor[64];
  const int t = threadIdx.x;
  const int g = blockIdx.x;
  const int n0 = g << 10;
  if (t < 64) hist[t] = 0;
  __syncthreads();
  int4 av = ((const int4*)(assign + n0))[t];   // nodes t*4 .. t*4+3
  atomicAdd(&hist[av.x], 1);
  atomicAdd(&hist[av.y], 1);
  atomicAdd(&hist[av.z], 1);
  atomicAdd(&hist[av.w], 1);
  __syncthreads();
  if (t == 0) {
    int s = 0;
    #pragma unroll
    for (int k = 0; k < 64; ++k) { offs[k] = s; s += hist[k]; }
    offs[64] = s;   // = 1024
  }
  __syncthreads();
  if (t < 64) cursor[t] = offs[t];
  if (t < 65) goff[g * 65 + t] = offs[t];
  __syncthreads();
  int p;
  p = atomicAdd(&cursor[av.x], 1); sorted[n0 + p] = n0 + t * 4 + 0;
  p = atomicAdd(&cursor[av.y], 1); sorted[n0 + p] = n0 + t * 4 + 1;
  p = atomicAdd(&cursor[av.z], 1); sorted[n0 + p] = n0 + t * 4 + 2;
  p = atomicAdd(&cursor[av.w], 1); sorted[n0 + p] = n0 + t * 4 + 3;
}

// ---------------------------------------------------------------------------
// Kernel 2b: pooled features via dense gather.
// 4096 blocks = (graph g, cluster k) x 256 threads (one output dim each).
// Sums the bin's member rows (avg 16) with unroll-4 independent loads;
// single plain store. No LDS, no atomics, 16 blocks/CU of TLP.
// ---------------------------------------------------------------------------
__global__ __launch_bounds__(256, 8) void gather_kernel(
    const float* __restrict__ x, const float* __restrict__ s1,
    const int* __restrict__ sorted, const int* __restrict__ goff,
    float* __restrict__ out)
{
  const int t = threadIdx.x;
  const int g = blockIdx.x >> 6;
  const int k = blockIdx.x & 63;
  const int o0 = goff[g * 65 + k];
  const int o1 = goff[g * 65 + k + 1];
  const int* sp = sorted + (g << 10);
  float sum = 0.f;
  int i = o0;
  for (; i + 4 <= o1; i += 4) {
    int n0 = sp[i], n1 = sp[i + 1], n2 = sp[i + 2], n3 = sp[i + 3];
    float w0 = s1[n0], w1 = s1[n1], w2 = s1[n2], w3 = s1[n3];
    float x0 = x[(size_t)n0 * DD + t];
    float x1 = x[(size_t)n1 * DD + t];
    float x2 = x[(size_t)n2 * DD + t];
    float x3 = x[(size_t)n3 * DD + t];
    sum += w0 * x0 + w1 * x1 + w2 * x2 + w3 * x3;
  }
  for (; i < o1; ++i) {
    int n = sp[i];
    sum += s1[n] * x[(size_t)n * DD + t];
  }
  out[((size_t)(g * 64 + k)) * DD + t] = sum;
}

// ---------------------------------------------------------------------------
// Kernel 3: edges -> out_adj. 256 blocks (4 per graph) x 1024 threads x 4
// edges. Per-block LDS adjacency accumulate (ds_add_f32), then streaming
// global atomicAdd combine (4 adds per output cell, distinct lines).
// ---------------------------------------------------------------------------
__global__ __launch_bounds__(1024, 2) void edge_kernel(
    const int* __restrict__ src, const int* __restrict__ dst,
    const float* __restrict__ ew, const int* __restrict__ assign,
    const float* __restrict__ s1, float* __restrict__ out_adj,
    float* __restrict__ sqA, float* __restrict__ crossA)
{
  __shared__ float adj[4096];           // 64x64 pooled adjacency (partial)
  const int t   = threadIdx.x;
  const int blk = blockIdx.x;
  const int g   = blk >> 2;
  #pragma unroll
  for (int i = 0; i < 4; ++i) adj[i * 1024 + t] = 0.f;
  __syncthreads();
  const int e0 = (g << 14) + ((blk & 3) << 12);   // 4096 edges per block
  float sq = 0.f, cr = 0.f;
  #pragma unroll
  for (int i = 0; i < 4; ++i) {
    int e = e0 + i * 1024 + t;
    int u = src[e], v = dst[e];
    float w = ew[e];
    int au = assign[u], av = assign[v];
    float contrib = w * s1[u] * s1[v];
    atomicAdd(&adj[au * 64 + av], contrib);   // ds_add_f32
    sq += w * w;
    if (au == av) cr += contrib;
  }
  #pragma unroll
  for (int off = 32; off; off >>= 1) {
    sq += __shfl_down(sq, off, 64);
    cr += __shfl_down(cr, off, 64);
  }
  if ((t & 63) == 0) {
    atomicAdd(&sqA[g], sq);
    atomicAdd(&crossA[g], cr);
  }
  __syncthreads();
  float* adjg = out_adj + (size_t)g * 4096;
  #pragma unroll
  for (int i = 0; i < 4; ++i)
    atomicAdd(&adjg[i * 1024 + t], adj[i * 1024 + t]);
}

// ---------------------------------------------------------------------------
// Kernel 4: link/entropy scalars + batch / batch_ptr tails.
// ---------------------------------------------------------------------------
__global__ __launch_bounds__(256) void finalize_kernel(
    const float* __restrict__ c, const float* __restrict__ sqA,
    const float* __restrict__ crossA, const float* __restrict__ ent_acc,
    float* __restrict__ out)
{
  const int t = threadIdx.x;
  float link = 0.f;
  if (t < 64) {
    const float* cg = c + t * 64;
    float ssq = 0.f;
    #pragma unroll
    for (int k = 0; k < 64; ++k) ssq += cg[k] * cg[k];
    float val = sqA[t] - 2.0f * crossA[t] + ssq;
    link = sqrtf(fmaxf(val, 0.f)) / 16384.0f;   // e_per = 16384
  }
  #pragma unroll
  for (int off = 32; off; off >>= 1) link += __shfl_down(link, off, 64);
  if (t == 0) {
    out[LINK_OFF] = link / 64.0f;
    out[ENT_OFF]  = ent_acc[0] / (float)NN;
  }
  for (int r = t; r < 4096; r += 256) out[BATCH_OFF + r] = (float)(r >> 6);
  for (int i = t; i < 65; i += 256)   out[BPTR_OFF + i]  = (float)(i << 6);
}

extern "C" void kernel_launch(void* const* d_in, const int* in_sizes, int n_in,
                              void* d_out, int out_size, void* d_ws, size_t ws_size,
                              hipStream_t stream) {
  const float* x    = (const float*)d_in[0];
  const float* ew   = (const float*)d_in[1];
  const float* Wm   = (const float*)d_in[2];
  const float* bvec = (const float*)d_in[3];
  const float* gum  = (const float*)d_in[4];
  const int*   eidx = (const int*)d_in[5];
  float* out = (float*)d_out;
  char*  ws  = (char*)d_ws;

  int*   assign = (int*)(ws + WS_ASSIGN);
  float* s1     = (float*)(ws + WS_S1);
  float* c      = (float*)(ws + WS_C);
  float* sqA    = (float*)(ws + WS_SQA);
  float* crossA = (float*)(ws + WS_CROSS);
  float* entacc = (float*)(ws + WS_ENT);
  int*   sorted = (int*)(ws + WS_SORT);
  int*   goff   = (int*)(ws + WS_GOFF);

  const int E = in_sizes[1];   // 1048576

  // zero the atomic accumulators + out_adj (combined via atomics)
  hipMemsetAsync(ws + WS_C, 0, (WS_ENT + 4) - WS_C, stream);
  hipMemsetAsync(out + ADJ_OFF, 0, (size_t)64 * 4096 * 4, stream);

  pool_assign_kernel<<<512, 256, 0, stream>>>(x, Wm, bvec, gum, assign, s1, c, entacc);
  sort_kernel<<<64, 256, 0, stream>>>(assign, sorted, goff);
  gather_kernel<<<4096, 256, 0, stream>>>(x, s1, sorted, goff, out + OUT_OFF);
  edge_kernel<<<256, 1024, 0, stream>>>(eidx, eidx + E, ew, assign, s1,
                                        out + ADJ_OFF, sqA, crossA);
  finalize_kernel<<<1, 256, 0, stream>>>(c, sqA, crossA, entacc, out);
}

// Round 4
// 102.689 us; speedup vs baseline: 1.6626x; 1.0175x over previous
//
#include <hip/hip_runtime.h>

// Problem constants (StochPool: B=64, N_PER=1024, D=256, K=64, DEG=16)
#define NN 65536           // total nodes
#define DD 256             // feature dim
#define KK 64              // pools per graph
#define NPG 1024           // nodes per graph

// d_out layout (flat float32, outputs concatenated in return order)
#define OUT_OFF   0          // (4096, 256)
#define ADJ_OFF   1048576    // (64, 64, 64)
#define LINK_OFF  1310720    // scalar
#define ENT_OFF   1310721    // scalar
#define BATCH_OFF 1310722    // (4096,) as float
#define BPTR_OFF  1314818    // (65,) as float

// ws layout (bytes)
#define WS_ASSIGN 0          // int32 x 65536
#define WS_S1     262144     // float x 65536
#define WS_C      524288     // float x 4096   (StS diagonal accum)
#define WS_SQA    540672     // float x 64
#define WS_CROSS  540928     // float x 64
#define WS_ENT    541184     // float x 1
#define WS_SORT   1048576    // int32 x 65536 (node ids sorted by cluster, per graph)
#define WS_GOFF   1310720    // int32 x 64*65 (per-graph bin offsets)
#define WS_ADJP   1331200    // float x 256*4096 (per-block adjacency partials, 4 MB)
#define WS_NEED   (WS_ADJP + 256 * 4096 * 4)

// ---------------------------------------------------------------------------
// Kernel 1: logits GEMM + in-register argmax/softmax stats per node.
// 1024 blocks x 256 threads; each block owns 64 consecutive nodes.
// Thread t: kq = t&7 -> k in [kq*8, kq*8+8); ng = t>>3 -> rows ng, ng+32.
// LDS: W d-slice [64][64] (16KB) + x tile [64][68] (17KB) -> 4 blocks/CU.
// Phase 2 is register-resident: each aligned 8-lane group holds one node's
// 64 logits (8 per lane); argmax/expsum via __shfl_xor(1,2,4).
// ---------------------------------------------------------------------------
__global__ __launch_bounds__(256, 4) void pool_assign_kernel(
    const float* __restrict__ x, const float* __restrict__ Wm,
    const float* __restrict__ bvec, const float* __restrict__ gum,
    int* __restrict__ assign, float* __restrict__ s1g,
    float* __restrict__ c_acc, float* __restrict__ ent_acc)
{
  __shared__ float lds_w[64 * 64];    // W slice: [d within chunk][k]
  __shared__ float lds_x[64 * 68];    // x tile (pad to 68 floats/row)
  __shared__ float esum[4];
  const int t   = threadIdx.x;
  const int kq  = t & 7;
  const int ng  = t >> 3;
  const int nb0 = blockIdx.x << 6;    // 64 nodes per block

  float bk[8];
  #pragma unroll
  for (int j = 0; j < 8; ++j) bk[j] = bvec[kq * 8 + j];

  float acc[2][8];
  #pragma unroll
  for (int i = 0; i < 2; ++i)
    #pragma unroll
    for (int j = 0; j < 8; ++j) acc[i][j] = 0.f;

  for (int ch = 0; ch < 4; ++ch) {
    const int d0 = ch << 6;
    // stage W rows d0..d0+63 (4096 contiguous floats)
    #pragma unroll
    for (int i = 0; i < 4; ++i) {
      int off = i * 1024 + t * 4;
      *(float4*)(&lds_w[off]) = *(const float4*)(Wm + d0 * 64 + off);
    }
    // stage x[nb0 + 0..63][d0 .. d0+63]
    #pragma unroll
    for (int it = 0; it < 4; ++it) {
      int r  = it * 16 + (t >> 4);
      int fi = (t & 15) << 2;
      *(float4*)(&lds_x[r * 68 + fi]) =
          *(const float4*)(x + (size_t)(nb0 + r) * DD + d0 + fi);
    }
    __syncthreads();
    #pragma unroll
    for (int d4 = 0; d4 < 16; ++d4) {
      float4 xv[2];
      #pragma unroll
      for (int i = 0; i < 2; ++i)
        xv[i] = *(const float4*)(&lds_x[(ng + 32 * i) * 68 + (d4 << 2)]);
      float4 wa[4], wb[4];
      #pragma unroll
      for (int m = 0; m < 4; ++m) {
        const float* wr = &lds_w[((d4 << 2) + m) * 64 + kq * 8];
        wa[m] = *(const float4*)wr;
        wb[m] = *(const float4*)(wr + 4);
      }
      #pragma unroll
      for (int i = 0; i < 2; ++i) {
        const float* xp = (const float*)&xv[i];
        #pragma unroll
        for (int m = 0; m < 4; ++m) {
          float xs = xp[m];
          acc[i][0] = fmaf(xs, wa[m].x, acc[i][0]);
          acc[i][1] = fmaf(xs, wa[m].y, acc[i][1]);
          acc[i][2] = fmaf(xs, wa[m].z, acc[i][2]);
          acc[i][3] = fmaf(xs, wa[m].w, acc[i][3]);
          acc[i][4] = fmaf(xs, wb[m].x, acc[i][4]);
          acc[i][5] = fmaf(xs, wb[m].y, acc[i][5]);
          acc[i][6] = fmaf(xs, wb[m].z, acc[i][6]);
          acc[i][7] = fmaf(xs, wb[m].w, acc[i][7]);
        }
      }
    }
    __syncthreads();
  }

  // phase 2: in-register softmax/argmax per node (8 lanes per node)
  float ent = 0.f;
  #pragma unroll
  for (int i = 0; i < 2; ++i) {
    const int nl = ng + 32 * i;
    const float* gp = gum + (size_t)(nb0 + nl) * KK + kq * 8;
    float4 g0 = *(const float4*)gp;
    float4 g1 = *(const float4*)(gp + 4);
    float z[8];
    z[0] = acc[i][0] + bk[0] + g0.x;
    z[1] = acc[i][1] + bk[1] + g0.y;
    z[2] = acc[i][2] + bk[2] + g0.z;
    z[3] = acc[i][3] + bk[3] + g0.w;
    z[4] = acc[i][4] + bk[4] + g1.x;
    z[5] = acc[i][5] + bk[5] + g1.y;
    z[6] = acc[i][6] + bk[6] + g1.z;
    z[7] = acc[i][7] + bk[7] + g1.w;
    float m = z[0]; int a = kq * 8;
    #pragma unroll
    for (int j = 1; j < 8; ++j)
      if (z[j] > m) { m = z[j]; a = kq * 8 + j; }   // strict > keeps first max
    // reduce (max, argmax) over the aligned 8-lane group; ties -> lower k
    #pragma unroll
    for (int off = 1; off <= 4; off <<= 1) {
      float mo = __shfl_xor(m, off, 64);
      int   ao = __shfl_xor(a, off, 64);
      if (mo > m || (mo == m && ao < a)) { m = mo; a = ao; }
    }
    float ls = 0.f;
    #pragma unroll
    for (int j = 0; j < 8; ++j) ls += expf(z[j] - m);
    #pragma unroll
    for (int off = 1; off <= 4; off <<= 1) ls += __shfl_xor(ls, off, 64);
    float p  = 1.0f / ls;                  // softmax value at argmax
    float s1 = (1.0f - p) + p;             // straight-through value (≈1)
    if (kq == 0) {
      size_t n_g = (size_t)nb0 + nl;
      int g = (int)(n_g >> 10);
      assign[n_g] = a;
      s1g[n_g]    = s1;
      atomicAdd(&c_acc[g * 64 + a], s1 * s1);
      ent += -s1 * logf(s1 + 1e-15f);      // non-argmax terms are exactly 0
    }
  }
  #pragma unroll
  for (int off = 32; off; off >>= 1) ent += __shfl_down(ent, off, 64);
  if ((t & 63) == 0) esum[t >> 6] = ent;
  __syncthreads();
  if (t == 0) atomicAdd(ent_acc, esum[0] + esum[1] + esum[2] + esum[3]);
}

// ---------------------------------------------------------------------------
// Kernel 2a: per-graph counting sort of nodes by cluster.
// 64 blocks (one per graph) x 256 threads x 4 nodes.
// ---------------------------------------------------------------------------
__global__ __launch_bounds__(256) void sort_kernel(
    const int* __restrict__ assign, int* __restrict__ sorted,
    int* __restrict__ goff)
{
  __shared__ int hist[64];
  __shared__ int offs[65];
  __shared__ int cursor[64];
  const int t = threadIdx.x;
  const int g = blockIdx.x;
  const int n0 = g << 10;
  if (t < 64) hist[t] = 0;
  __syncthreads();
  int4 av = ((const int4*)(assign + n0))[t];   // nodes t*4 .. t*4+3
  atomicAdd(&hist[av.x], 1);
  atomicAdd(&hist[av.y], 1);
  atomicAdd(&hist[av.z], 1);
  atomicAdd(&hist[av.w], 1);
  __syncthreads();
  if (t == 0) {
    int s = 0;
    #pragma unroll
    for (int k = 0; k < 64; ++k) { offs[k] = s; s += hist[k]; }
    offs[64] = s;   // = 1024
  }
  __syncthreads();
  if (t < 64) cursor[t] = offs[t];
  if (t < 65) goff[g * 65 + t] = offs[t];
  __syncthreads();
  int p;
  p = atomicAdd(&cursor[av.x], 1); sorted[n0 + p] = n0 + t * 4 + 0;
  p = atomicAdd(&cursor[av.y], 1); sorted[n0 + p] = n0 + t * 4 + 1;
  p = atomicAdd(&cursor[av.z], 1); sorted[n0 + p] = n0 + t * 4 + 2;
  p = atomicAdd(&cursor[av.w], 1); sorted[n0 + p] = n0 + t * 4 + 3;
}

// ---------------------------------------------------------------------------
// Kernel 2b: pooled features via dense gather.
// 4096 blocks = (graph g, cluster k) x 256 threads (one output dim each).
// ---------------------------------------------------------------------------
__global__ __launch_bounds__(256, 8) void gather_kernel(
    const float* __restrict__ x, const float* __restrict__ s1,
    const int* __restrict__ sorted, const int* __restrict__ goff,
    float* __restrict__ out)
{
  const int t = threadIdx.x;
  const int g = blockIdx.x >> 6;
  const int k = blockIdx.x & 63;
  const int o0 = goff[g * 65 + k];
  const int o1 = goff[g * 65 + k + 1];
  const int* sp = sorted + (g << 10);
  float sum = 0.f;
  int i = o0;
  for (; i + 4 <= o1; i += 4) {
    int n0 = sp[i], n1 = sp[i + 1], n2 = sp[i + 2], n3 = sp[i + 3];
    float w0 = s1[n0], w1 = s1[n1], w2 = s1[n2], w3 = s1[n3];
    float x0 = x[(size_t)n0 * DD + t];
    float x1 = x[(size_t)n1 * DD + t];
    float x2 = x[(size_t)n2 * DD + t];
    float x3 = x[(size_t)n3 * DD + t];
    sum += w0 * x0 + w1 * x1 + w2 * x2 + w3 * x3;
  }
  for (; i < o1; ++i) {
    int n = sp[i];
    sum += s1[n] * x[(size_t)n * DD + t];
  }
  out[((size_t)(g * 64 + k)) * DD + t] = sum;
}

// ---------------------------------------------------------------------------
// Kernel 3: edges -> per-block LDS adjacency, plain-stored partials in ws.
// 256 blocks (4 per graph) x 1024 threads x 4 edges.
// ---------------------------------------------------------------------------
__global__ __launch_bounds__(1024, 2) void edge_kernel(
    const int* __restrict__ src, const int* __restrict__ dst,
    const float* __restrict__ ew, const int* __restrict__ assign,
    const float* __restrict__ s1, float* __restrict__ adj_partial,
    float* __restrict__ sqA, float* __restrict__ crossA)
{
  __shared__ float adj[4096];           // 64x64 pooled adjacency (partial)
  const int t   = threadIdx.x;
  const int blk = blockIdx.x;
  const int g   = blk >> 2;
  #pragma unroll
  for (int i = 0; i < 4; ++i) adj[i * 1024 + t] = 0.f;
  __syncthreads();
  const int e0 = (g << 14) + ((blk & 3) << 12);   // 4096 edges per block
  float sq = 0.f, cr = 0.f;
  #pragma unroll
  for (int i = 0; i < 4; ++i) {
    int e = e0 + i * 1024 + t;
    int u = src[e], v = dst[e];
    float w = ew[e];
    int au = assign[u], av = assign[v];
    float contrib = w * s1[u] * s1[v];
    atomicAdd(&adj[au * 64 + av], contrib);   // ds_add_f32
    sq += w * w;
    if (au == av) cr += contrib;
  }
  #pragma unroll
  for (int off = 32; off; off >>= 1) {
    sq += __shfl_down(sq, off, 64);
    cr += __shfl_down(cr, off, 64);
  }
  if ((t & 63) == 0) {
    atomicAdd(&sqA[g], sq);
    atomicAdd(&crossA[g], cr);
  }
  __syncthreads();
  float* pp = adj_partial + (size_t)blk * 4096;
  #pragma unroll
  for (int i = 0; i < 4; ++i) pp[i * 1024 + t] = adj[i * 1024 + t];
}

// Combine 4 partials per graph -> out_adj (plain stores, fully overwrites).
__global__ __launch_bounds__(1024) void adj_combine_kernel(
    const float* __restrict__ adj_partial, float* __restrict__ out_adj)
{
  int idx = blockIdx.x * 1024 + threadIdx.x;   // 262144 cells
  int g = idx >> 12;
  int cell = idx & 4095;
  const float* p = adj_partial + ((size_t)(g * 4)) * 4096 + cell;
  out_adj[idx] = p[0] + p[4096] + p[8192] + p[12288];
}

// Fallback (small ws): global-atomic combine, needs out_adj pre-zeroed.
__global__ __launch_bounds__(1024, 2) void edge_kernel_atomic(
    const int* __restrict__ src, const int* __restrict__ dst,
    const float* __restrict__ ew, const int* __restrict__ assign,
    const float* __restrict__ s1, float* __restrict__ out_adj,
    float* __restrict__ sqA, float* __restrict__ crossA)
{
  __shared__ float adj[4096];
  const int t   = threadIdx.x;
  const int blk = blockIdx.x;
  const int g   = blk >> 2;
  #pragma unroll
  for (int i = 0; i < 4; ++i) adj[i * 1024 + t] = 0.f;
  __syncthreads();
  const int e0 = (g << 14) + ((blk & 3) << 12);
  float sq = 0.f, cr = 0.f;
  #pragma unroll
  for (int i = 0; i < 4; ++i) {
    int e = e0 + i * 1024 + t;
    int u = src[e], v = dst[e];
    float w = ew[e];
    int au = assign[u], av = assign[v];
    float contrib = w * s1[u] * s1[v];
    atomicAdd(&adj[au * 64 + av], contrib);
    sq += w * w;
    if (au == av) cr += contrib;
  }
  #pragma unroll
  for (int off = 32; off; off >>= 1) {
    sq += __shfl_down(sq, off, 64);
    cr += __shfl_down(cr, off, 64);
  }
  if ((t & 63) == 0) {
    atomicAdd(&sqA[g], sq);
    atomicAdd(&crossA[g], cr);
  }
  __syncthreads();
  float* adjg = out_adj + (size_t)g * 4096;
  #pragma unroll
  for (int i = 0; i < 4; ++i)
    atomicAdd(&adjg[i * 1024 + t], adj[i * 1024 + t]);
}

// ---------------------------------------------------------------------------
// Kernel 4: link/entropy scalars + batch / batch_ptr tails.
// ---------------------------------------------------------------------------
__global__ __launch_bounds__(256) void finalize_kernel(
    const float* __restrict__ c, const float* __restrict__ sqA,
    const float* __restrict__ crossA, const float* __restrict__ ent_acc,
    float* __restrict__ out)
{
  const int t = threadIdx.x;
  float link = 0.f;
  if (t < 64) {
    const float* cg = c + t * 64;
    float ssq = 0.f;
    #pragma unroll
    for (int k = 0; k < 64; ++k) ssq += cg[k] * cg[k];
    float val = sqA[t] - 2.0f * crossA[t] + ssq;
    link = sqrtf(fmaxf(val, 0.f)) / 16384.0f;   // e_per = 16384
  }
  #pragma unroll
  for (int off = 32; off; off >>= 1) link += __shfl_down(link, off, 64);
  if (t == 0) {
    out[LINK_OFF] = link / 64.0f;
    out[ENT_OFF]  = ent_acc[0] / (float)NN;
  }
  for (int r = t; r < 4096; r += 256) out[BATCH_OFF + r] = (float)(r >> 6);
  for (int i = t; i < 65; i += 256)   out[BPTR_OFF + i]  = (float)(i << 6);
}

extern "C" void kernel_launch(void* const* d_in, const int* in_sizes, int n_in,
                              void* d_out, int out_size, void* d_ws, size_t ws_size,
                              hipStream_t stream) {
  const float* x    = (const float*)d_in[0];
  const float* ew   = (const float*)d_in[1];
  const float* Wm   = (const float*)d_in[2];
  const float* bvec = (const float*)d_in[3];
  const float* gum  = (const float*)d_in[4];
  const int*   eidx = (const int*)d_in[5];
  float* out = (float*)d_out;
  char*  ws  = (char*)d_ws;

  int*   assign = (int*)(ws + WS_ASSIGN);
  float* s1     = (float*)(ws + WS_S1);
  float* c      = (float*)(ws + WS_C);
  float* sqA    = (float*)(ws + WS_SQA);
  float* crossA = (float*)(ws + WS_CROSS);
  float* entacc = (float*)(ws + WS_ENT);
  int*   sorted = (int*)(ws + WS_SORT);
  int*   goff   = (int*)(ws + WS_GOFF);
  float* adjp   = (float*)(ws + WS_ADJP);

  const int E = in_sizes[1];   // 1048576

  // zero the small atomic accumulators (c, sqA, crossA, ent)
  hipMemsetAsync(ws + WS_C, 0, (WS_ENT + 4) - WS_C, stream);

  pool_assign_kernel<<<1024, 256, 0, stream>>>(x, Wm, bvec, gum, assign, s1, c, entacc);
  sort_kernel<<<64, 256, 0, stream>>>(assign, sorted, goff);
  gather_kernel<<<4096, 256, 0, stream>>>(x, s1, sorted, goff, out + OUT_OFF);
  if (ws_size >= (size_t)WS_NEED) {
    edge_kernel<<<256, 1024, 0, stream>>>(eidx, eidx + E, ew, assign, s1,
                                          adjp, sqA, crossA);
    adj_combine_kernel<<<256, 1024, 0, stream>>>(adjp, out + ADJ_OFF);
  } else {
    hipMemsetAsync(out + ADJ_OFF, 0, (size_t)64 * 4096 * 4, stream);
    edge_kernel_atomic<<<256, 1024, 0, stream>>>(eidx, eidx + E, ew, assign, s1,
                                                 out + ADJ_OFF, sqA, crossA);
  }
  finalize_kernel<<<1, 256, 0, stream>>>(c, sqA, crossA, entacc, out);
}